// Round 3
// baseline (225.147 us; speedup 1.0000x reference)
//
#include <hip/hip_runtime.h>
#include <hip/hip_bf16.h>
#include <stdint.h>

#define B_DIM 8
#define S_LEN 2048
#define DMODEL 2048
#define HDIM 128

typedef __attribute__((ext_vector_type(4))) float f32x4;
typedef __attribute__((ext_vector_type(8))) short bf16x8;
typedef __attribute__((ext_vector_type(4))) unsigned int u32x4;
typedef unsigned short u16;
typedef unsigned int u32;

__device__ __forceinline__ u16 f2bf(float f) {
    union { float f; u32 u; } v; v.f = f;
    u32 u = v.u;
    u32 r = (u + 0x7fffu + ((u >> 16) & 1u)) >> 16;
    return (u16)r;
}

__device__ __forceinline__ u32 pk2bf(float a, float b) {
    float2 f2; f2.x = a; f2.y = b;
    __hip_bfloat162 h = __float22bfloat162_rn(f2);
    union { __hip_bfloat162 h; u32 u; } cv; cv.h = h;
    return cv.u;
}

__device__ __forceinline__ void async_copy16(u16* lds, const u16* g) {
    __builtin_amdgcn_global_load_lds((const __attribute__((address_space(1))) u32*)g,
                                     (__attribute__((address_space(3))) u32*)lds,
                                     16, 0, 0);
}

// ---------------- pack weights: transpose [2048 k][128 h] fp32 x3 -> bf16 Wp[384 h][2048 k]
__global__ void pack_weights(const float* __restrict__ Wq, const float* __restrict__ Wk,
                             const float* __restrict__ Wv, u16* __restrict__ Wp) {
    __shared__ u16 tl[64 * 64];
    int t = threadIdx.x;
    int bx = blockIdx.x;                 // 3 w * 32 kt * 2 ht = 192
    int w = bx >> 6;
    int kt = (bx >> 1) & 31;
    int ht = bx & 1;
    int k0 = kt * 64, h0 = ht * 64;
    const float* W = (w == 0) ? Wq : ((w == 1) ? Wk : Wv);

    int kl = t >> 2, hc = t & 3;
    const float* src = W + (size_t)(k0 + kl) * HDIM + h0 + hc * 16;
#pragma unroll
    for (int half = 0; half < 2; half++) {
        bf16x8 p;
#pragma unroll
        for (int j = 0; j < 8; j++) p[j] = (short)f2bf(src[half * 8 + j]);
        int slot = hc * 2 + half;
        *(bf16x8*)((char*)tl + kl * 128 + ((slot ^ (kl & 7)) << 4)) = p;
    }
    __syncthreads();
    int hl = t >> 2, kc = t & 3;
    u16* dst = Wp + (size_t)(w * HDIM + h0 + hl) * DMODEL + k0 + kc * 16;
#pragma unroll
    for (int half = 0; half < 2; half++) {
        bf16x8 p;
#pragma unroll
        for (int j = 0; j < 8; j++) {
            int k = kc * 16 + half * 8 + j;
            p[j] = *(u16*)((char*)tl + k * 128 + (((hl >> 3) ^ (k & 7)) << 4) + (hl & 7) * 2);
        }
        *(bf16x8*)(dst + half * 8) = p;
    }
}

// ---------------- fused QKV projection GEMM: [16384,2048] @ [2048,384] (bf16 MFMA)
// BM=64, BN=384 (A read ONCE), BK=64, 8 waves (2m x 4n, wave tile 32x96), double-buffered.
__launch_bounds__(512, 2)
__global__ void qkv_gemm(const float* __restrict__ hs, const u16* __restrict__ Wp,
                         const float* __restrict__ bq, const float* __restrict__ bk,
                         const float* __restrict__ bv,
                         u16* __restrict__ Qb, u16* __restrict__ Kb, u16* __restrict__ Vb) {
    __shared__ u16 As[2][64 * 64];       // 2 x 8 KB
    __shared__ u16 Bs[2][384 * 64];      // 2 x 48 KB

    int t = threadIdx.x;
    int wv = t >> 6, l = t & 63, lr = l & 15, lq = l >> 4;
    int wm = wv >> 2, wn = wv & 3;
    int m0 = blockIdx.x * 64;

    f32x4 acc[2][6] = {};

    int ar = t >> 3, aq = t & 7;         // A staging: row, 8-float chunk
    const float* gA = hs + (size_t)(m0 + ar) * DMODEL + aq * 8;

    f32x4 av0, av1;

#define LOAD_A(K0)                                                     \
    {                                                                  \
        av0 = *(const f32x4*)(gA + (K0));                              \
        av1 = *(const f32x4*)(gA + (K0) + 4);                          \
    }
#define STAGE_B(K0, BUF)                                               \
    {                                                                  \
        _Pragma("unroll")                                              \
        for (int i = 0; i < 6; i++) {                                  \
            int c = i * 512 + t;                                       \
            int n = c >> 3, s = c & 7;                                 \
            async_copy16(&Bs[BUF][c * 8],                              \
                         Wp + (size_t)n * DMODEL + (K0) + ((s ^ (n & 7)) * 8)); \
        }                                                              \
    }
#define WRITE_A(BUF)                                                   \
    {                                                                  \
        u32x4 p;                                                       \
        p.x = pk2bf(av0[0], av0[1]); p.y = pk2bf(av0[2], av0[3]);      \
        p.z = pk2bf(av1[0], av1[1]); p.w = pk2bf(av1[2], av1[3]);      \
        *(u32x4*)((char*)&As[BUF][0] + ar * 128 + ((aq ^ (ar & 7)) << 4)) = p; \
    }

    LOAD_A(0);
    STAGE_B(0, 0);
    WRITE_A(0);
    __syncthreads();

    int cur = 0;
    for (int k0 = 0; k0 < DMODEL; k0 += 64) {
        int kn = (k0 + 64) & (DMODEL - 1);   // wraps on last step (junk prefetch, unused)
        LOAD_A(kn);
        STAGE_B(kn, cur ^ 1);
#pragma unroll
        for (int kk = 0; kk < 2; kk++) {
            bf16x8 a[2], b[6];
            int slot = kk * 4 + lq;
#pragma unroll
            for (int mi = 0; mi < 2; mi++) {
                int row = wm * 32 + mi * 16 + lr;
                a[mi] = *(bf16x8*)((char*)&As[cur][0] + row * 128 + ((slot ^ (row & 7)) << 4));
            }
#pragma unroll
            for (int ni = 0; ni < 6; ni++) {
                int row = wn * 96 + ni * 16 + lr;
                b[ni] = *(bf16x8*)((char*)&Bs[cur][0] + row * 128 + ((slot ^ (row & 7)) << 4));
            }
            __builtin_amdgcn_s_setprio(1);
#pragma unroll
            for (int mi = 0; mi < 2; mi++)
#pragma unroll
                for (int ni = 0; ni < 6; ni++)
                    acc[mi][ni] = __builtin_amdgcn_mfma_f32_16x16x32_bf16(a[mi], b[ni], acc[mi][ni], 0, 0, 0);
            __builtin_amdgcn_s_setprio(0);
        }
        WRITE_A(cur ^ 1);
        __syncthreads();
        cur ^= 1;
    }

    // epilogue: bias, Q pre-scale by 1/sqrt(128), store bf16
#pragma unroll
    for (int ni = 0; ni < 6; ni++) {
        int col = wn * 96 + ni * 16 + lr;
        int w = col >> 7, h = col & 127;
        const float* bp = (w == 0) ? bq : ((w == 1) ? bk : bv);
        float bias = bp[h];
        float scale = (w == 0) ? 0.08838834764831845f : 1.0f;
        u16* dst = (w == 0) ? Qb : ((w == 1) ? Kb : Vb);
#pragma unroll
        for (int mi = 0; mi < 2; mi++) {
#pragma unroll
            for (int r = 0; r < 4; r++) {
                int row = m0 + wm * 32 + mi * 16 + lq * 4 + r;
                dst[(size_t)row * HDIM + h] = f2bf((acc[mi][ni][r] + bias) * scale);
            }
        }
    }
#undef LOAD_A
#undef STAGE_B
#undef WRITE_A
}

// ---------------- V transpose: [b][s][d] -> [b][d][s] (bf16), LDS-tiled 64x64
__global__ void transpose_v(const u16* __restrict__ Vb, u16* __restrict__ Vt) {
    __shared__ u16 tl[64 * 64];
    int t = threadIdx.x;
    int bx = blockIdx.x;                 // 8 b * 32 st * 2 dt = 512
    int b = bx >> 6;
    int st = (bx >> 1) & 31;
    int dt = bx & 1;
    int s0 = st * 64, d0 = dt * 64;

    int sl = t >> 2, dc = t & 3;
    const u16* src = Vb + (size_t)(b * S_LEN + s0 + sl) * HDIM + d0 + dc * 16;
#pragma unroll
    for (int half = 0; half < 2; half++) {
        bf16x8 p = *(const bf16x8*)(src + half * 8);
        int slot = dc * 2 + half;
        *(bf16x8*)((char*)tl + sl * 128 + ((slot ^ (sl & 7)) << 4)) = p;
    }
    __syncthreads();
    int dl = t >> 2, sc = t & 3;
    u16* dst = Vt + (size_t)(b * HDIM + d0 + dl) * S_LEN + s0 + sc * 16;
#pragma unroll
    for (int half = 0; half < 2; half++) {
        bf16x8 p;
#pragma unroll
        for (int j = 0; j < 8; j++) {
            int s = sc * 16 + half * 8 + j;
            p[j] = *(u16*)((char*)tl + s * 128 + (((dl >> 3) ^ (s & 7)) << 4) + (dl & 7) * 2);
        }
        *(bf16x8*)(dst + half * 8) = p;
    }
}

// ---------------- causal flash attention: 1 wave / 16 q-rows, barrier-free,
// K/V read directly from L2 (KV is L2-resident per-XCD with b = bx&7 mapping).
__launch_bounds__(64, 3)
__global__ void attn(const u16* __restrict__ Qb, const u16* __restrict__ Kb,
                     const u16* __restrict__ Vt, float* __restrict__ out) {
    __shared__ u16 Pw[16 * 64];          // 2 KB wave-private P tile, swizzled

    int t = threadIdx.x;
    int lr = t & 15, lq = t >> 4;
    int bx = blockIdx.x;                 // 1024 = 8 b * 128 qt
    int b = bx & 7;                      // batch == XCD for KV L2 locality
    int qt = 127 - (bx >> 3);            // descending work order: heavy tiles first
    int qr0 = qt * 16;
    size_t qbase = (size_t)b * S_LEN;

    // Q fragments (pre-scaled at projection time)
    bf16x8 aqf[4];
#pragma unroll
    for (int kk = 0; kk < 4; kk++)
        aqf[kk] = *(const bf16x8*)(Qb + (qbase + qr0 + lr) * HDIM + kk * 32 + lq * 8);

    f32x4 o_acc[8] = {};
    float m_run[4], l_run[4];
#pragma unroll
    for (int r = 0; r < 4; r++) { m_run[r] = -1e38f; l_run[r] = 0.f; }

    int nkt = (qt >> 2) + 1;
    int ktd = qt >> 2;
    const u16* Kbase = Kb + qbase * HDIM;
    const u16* Vbase = Vt + (size_t)b * HDIM * S_LEN;

    for (int kt = 0; kt < nkt; ++kt) {
        int kv0 = kt * 64;

        // S = Q K^T : K fragments straight from global (L2-hit)
        f32x4 sa[4] = {};
#pragma unroll
        for (int kk = 0; kk < 4; kk++) {
            bf16x8 bk8[4];
#pragma unroll
            for (int n = 0; n < 4; n++)
                bk8[n] = *(const bf16x8*)(Kbase + (size_t)(kv0 + n * 16 + lr) * HDIM + kk * 32 + lq * 8);
            __builtin_amdgcn_s_setprio(1);
#pragma unroll
            for (int n = 0; n < 4; n++)
                sa[n] = __builtin_amdgcn_mfma_f32_16x16x32_bf16(aqf[kk], bk8[n], sa[n], 0, 0, 0);
            __builtin_amdgcn_s_setprio(0);
        }

        // causal mask on the diagonal tile
        if (kt == ktd) {
#pragma unroll
            for (int n = 0; n < 4; n++) {
                int col = kv0 + n * 16 + lr;
#pragma unroll
                for (int r = 0; r < 4; r++) {
                    int row = qr0 + lq * 4 + r;
                    if (col > row) sa[n][r] = -1e30f;
                }
            }
        }

        // online softmax (16-lane groups own 4 q-rows each)
        float pexp[4][4];
#pragma unroll
        for (int r = 0; r < 4; r++) {
            float mx = fmaxf(fmaxf(sa[0][r], sa[1][r]), fmaxf(sa[2][r], sa[3][r]));
#pragma unroll
            for (int off = 8; off >= 1; off >>= 1) mx = fmaxf(mx, __shfl_xor(mx, off, 64));
            float mnew = fmaxf(m_run[r], mx);
            float f = __expf(m_run[r] - mnew);
            float rs = 0.f;
#pragma unroll
            for (int n = 0; n < 4; n++) { float e = __expf(sa[n][r] - mnew); pexp[n][r] = e; rs += e; }
#pragma unroll
            for (int off = 8; off >= 1; off >>= 1) rs += __shfl_xor(rs, off, 64);
            l_run[r] = l_run[r] * f + rs;
            m_run[r] = mnew;
#pragma unroll
            for (int n = 0; n < 8; n++) o_acc[n][r] *= f;
        }

        // P -> wave-private LDS (single wave: lgkm ordering suffices, no barrier)
#pragma unroll
        for (int n = 0; n < 4; n++) {
            int col = n * 16 + lr;
            int slot = col >> 3;
            int within = (col & 7) * 2;
#pragma unroll
            for (int r = 0; r < 4; r++) {
                int row = lq * 4 + r;
                *(u16*)((char*)Pw + row * 128 + ((slot ^ (row & 7)) << 4) + within) = f2bf(pexp[n][r]);
            }
        }

        // O += P V : V fragments straight from global (L2-hit)
#pragma unroll
        for (int kk = 0; kk < 2; kk++) {
            int slot = kk * 4 + lq;
            bf16x8 pa = *(bf16x8*)((char*)Pw + lr * 128 + ((slot ^ (lr & 7)) << 4));
#pragma unroll
            for (int n = 0; n < 8; n++) {
                bf16x8 vb8 = *(const bf16x8*)(Vbase + (size_t)(n * 16 + lr) * S_LEN + kv0 + kk * 32 + lq * 8);
                __builtin_amdgcn_s_setprio(1);
                o_acc[n] = __builtin_amdgcn_mfma_f32_16x16x32_bf16(pa, vb8, o_acc[n], 0, 0, 0);
                __builtin_amdgcn_s_setprio(0);
            }
        }
    }

    // epilogue: normalize and store fp32
#pragma unroll
    for (int r = 0; r < 4; r++) {
        float inv = 1.0f / l_run[r];
        int row = qr0 + lq * 4 + r;
#pragma unroll
        for (int n = 0; n < 8; n++) {
            int col = n * 16 + lr;
            out[(qbase + row) * HDIM + col] = o_acc[n][r] * inv;
        }
    }
}

extern "C" void kernel_launch(void* const* d_in, const int* in_sizes, int n_in,
                              void* d_out, int out_size, void* d_ws, size_t ws_size,
                              hipStream_t stream) {
    const float* hs = (const float*)d_in[0];
    const float* Wq = (const float*)d_in[1];
    const float* bq = (const float*)d_in[2];
    const float* Wk = (const float*)d_in[3];
    const float* bk = (const float*)d_in[4];
    const float* Wv = (const float*)d_in[5];
    const float* bv = (const float*)d_in[6];
    float* out = (float*)d_out;

    char* ws = (char*)d_ws;
    u16* Qb = (u16*)(ws);                       // 4 MB  [16384][128] bf16 (pre-scaled)
    u16* Kb = (u16*)(ws + (size_t)(4  << 20));  // 4 MB
    u16* Vb = (u16*)(ws + (size_t)(8  << 20));  // 4 MB
    u16* Vt = (u16*)(ws + (size_t)(12 << 20));  // 4 MB  [8][128][2048]
    u16* Wp = (u16*)(ws + (size_t)(16 << 20));  // 1.5 MB [384][2048]

    hipLaunchKernelGGL(pack_weights, dim3(192), dim3(256), 0, stream, Wq, Wk, Wv, Wp);
    hipLaunchKernelGGL(qkv_gemm, dim3(256), dim3(512), 0, stream, hs, Wp, bq, bk, bv, Qb, Kb, Vb);
    hipLaunchKernelGGL(transpose_v, dim3(512), dim3(256), 0, stream, Vb, Vt);
    hipLaunchKernelGGL(attn, dim3(1024), dim3(64), 0, stream, Qb, Kb, Vt, out);
}

// Round 4
// 172.839 us; speedup vs baseline: 1.3026x; 1.3026x over previous
//
#include <hip/hip_runtime.h>
#include <hip/hip_bf16.h>
#include <stdint.h>

#define B_DIM 8
#define S_LEN 2048
#define DMODEL 2048
#define HDIM 128

typedef __attribute__((ext_vector_type(4))) float f32x4;
typedef __attribute__((ext_vector_type(8))) short bf16x8;
typedef unsigned short u16;
typedef unsigned int u32;

__device__ __forceinline__ u16 f2bf(float f) {
    union { float f; u32 u; } v; v.f = f;
    u32 u = v.u;
    u32 r = (u + 0x7fffu + ((u >> 16) & 1u)) >> 16;
    return (u16)r;
}

__device__ __forceinline__ u32 pk2bf(float a, float b) {
    float2 f2; f2.x = a; f2.y = b;
    __hip_bfloat162 h = __float22bfloat162_rn(f2);
    union { __hip_bfloat162 h; u32 u; } cv; cv.h = h;
    return cv.u;
}

__device__ __forceinline__ void async_copy16(u16* lds, const u16* g) {
    __builtin_amdgcn_global_load_lds((const __attribute__((address_space(1))) u32*)g,
                                     (__attribute__((address_space(3))) u32*)lds,
                                     16, 0, 0);
}

// ---------------- pack weights: transpose [2048 k][128 h] fp32 x3 -> bf16 Wp[384 h][2048 k]
__global__ void pack_weights(const float* __restrict__ Wq, const float* __restrict__ Wk,
                             const float* __restrict__ Wv, u16* __restrict__ Wp) {
    __shared__ u16 tl[64 * 64];
    int t = threadIdx.x;
    int bx = blockIdx.x;                 // 3 w * 32 kt * 2 ht = 192
    int w = bx >> 6;
    int kt = (bx >> 1) & 31;
    int ht = bx & 1;
    int k0 = kt * 64, h0 = ht * 64;
    const float* W = (w == 0) ? Wq : ((w == 1) ? Wk : Wv);

    int kl = t >> 2, hc = t & 3;
    const float* src = W + (size_t)(k0 + kl) * HDIM + h0 + hc * 16;
#pragma unroll
    for (int half = 0; half < 2; half++) {
        bf16x8 p;
#pragma unroll
        for (int j = 0; j < 8; j++) p[j] = (short)f2bf(src[half * 8 + j]);
        int slot = hc * 2 + half;
        *(bf16x8*)((char*)tl + kl * 128 + ((slot ^ (kl & 7)) << 4)) = p;
    }
    __syncthreads();
    int hl = t >> 2, kc = t & 3;
    u16* dst = Wp + (size_t)(w * HDIM + h0 + hl) * DMODEL + k0 + kc * 16;
#pragma unroll
    for (int half = 0; half < 2; half++) {
        bf16x8 p;
#pragma unroll
        for (int j = 0; j < 8; j++) {
            int k = kc * 16 + half * 8 + j;
            p[j] = *(u16*)((char*)tl + k * 128 + (((hl >> 3) ^ (k & 7)) << 4) + (hl & 7) * 2);
        }
        *(bf16x8*)(dst + half * 8) = p;
    }
}

// ---------------- fused QKV projection GEMM: [16384,2048] @ [2048,384] (bf16 MFMA)
// BM=32, BN=384 (A read once), BK=32: grid 512 -> 2 blocks/CU, 16 waves/CU = 4/SIMD.
// 8 waves = 2m x 4n, wave tile 16x96, acc[6]. Paired-line XOR swizzle (rows of 128B hold
// 2 logical rows; phys_slot = ((row&1)*4 + kchunk) ^ ((row>>1)&7)) -> 2-way reads (free).
__launch_bounds__(512, 4)
__global__ void qkv_gemm(const float* __restrict__ hs, const u16* __restrict__ Wp,
                         const float* __restrict__ bq, const float* __restrict__ bk,
                         const float* __restrict__ bv,
                         u16* __restrict__ Qb, u16* __restrict__ Kb, u16* __restrict__ Vb) {
    __shared__ u16 As[2][32 * 32];       // 2 x 2 KB
    __shared__ u16 Bs[2][384 * 32];      // 2 x 24 KB

    int t = threadIdx.x;
    int wv = t >> 6, l = t & 63, lr = l & 15, lq = l >> 4;
    int wm = wv >> 2, wn = wv & 3;
    int m0 = blockIdx.x * 32;

    f32x4 acc[6] = {};

    int ar = t >> 4, aq = t & 15;        // A staging: row 0..31, 2-float chunk 0..15
    const float* gA = hs + (size_t)(m0 + ar) * DMODEL + aq * 2;
    float2 av;

#define LOAD_A(K0) { av = *(const float2*)(gA + (K0)); }
#define STAGE_B(K0, BUF)                                                   \
    {                                                                      \
        _Pragma("unroll")                                                  \
        for (int i = 0; i < 3; i++) {                                      \
            int c = i * 512 + t;                                           \
            int line = c >> 3, ps = c & 7, ls = ps ^ (line & 7);           \
            int n = line * 2 + (ls >> 2), kc = ls & 3;                     \
            async_copy16(&Bs[BUF][c * 8], Wp + (size_t)n * DMODEL + (K0) + kc * 8); \
        }                                                                  \
    }
#define WRITE_A(BUF)                                                       \
    {                                                                      \
        u32 p = pk2bf(av.x, av.y);                                         \
        int line = ar >> 1;                                                \
        int ls = (ar & 1) * 4 + (aq >> 2);                                 \
        *(u32*)((char*)&As[BUF][0] + line * 128 + ((ls ^ (line & 7)) << 4) + (aq & 3) * 4) = p; \
    }

    LOAD_A(0);
    STAGE_B(0, 0);
    WRITE_A(0);
    __syncthreads();

    int cur = 0;
    for (int k0 = 0; k0 < DMODEL; k0 += 32) {
        int kn = (k0 + 32) & (DMODEL - 1);   // wraps on last step (junk prefetch, unused)
        LOAD_A(kn);
        STAGE_B(kn, cur ^ 1);

        bf16x8 a, bfr[6];
        {
            int row = wm * 16 + lr;
            int line = row >> 1, ls = (row & 1) * 4 + lq;
            a = *(bf16x8*)((char*)&As[cur][0] + line * 128 + ((ls ^ (line & 7)) << 4));
        }
#pragma unroll
        for (int ni = 0; ni < 6; ni++) {
            int row = wn * 96 + ni * 16 + lr;
            int line = row >> 1, ls = (row & 1) * 4 + lq;
            bfr[ni] = *(bf16x8*)((char*)&Bs[cur][0] + line * 128 + ((ls ^ (line & 7)) << 4));
        }
        __builtin_amdgcn_s_setprio(1);
#pragma unroll
        for (int ni = 0; ni < 6; ni++)
            acc[ni] = __builtin_amdgcn_mfma_f32_16x16x32_bf16(a, bfr[ni], acc[ni], 0, 0, 0);
        __builtin_amdgcn_s_setprio(0);

        WRITE_A(cur ^ 1);
        __syncthreads();
        cur ^= 1;
    }

    // epilogue: bias, Q pre-scale by 1/sqrt(128), store bf16
#pragma unroll
    for (int ni = 0; ni < 6; ni++) {
        int col = wn * 96 + ni * 16 + lr;
        int w = col >> 7, h = col & 127;
        const float* bp = (w == 0) ? bq : ((w == 1) ? bk : bv);
        float bias = bp[h];
        float scale = (w == 0) ? 0.08838834764831845f : 1.0f;
        u16* dst = (w == 0) ? Qb : ((w == 1) ? Kb : Vb);
#pragma unroll
        for (int r = 0; r < 4; r++) {
            int row = m0 + wm * 16 + lq * 4 + r;
            dst[(size_t)row * HDIM + h] = f2bf((acc[ni][r] + bias) * scale);
        }
    }
#undef LOAD_A
#undef STAGE_B
#undef WRITE_A
}

// ---------------- V transpose: [b][s][d] -> [b][d][s] (bf16), LDS-tiled 64x64
__global__ void transpose_v(const u16* __restrict__ Vb, u16* __restrict__ Vt) {
    __shared__ u16 tl[64 * 64];
    int t = threadIdx.x;
    int bx = blockIdx.x;                 // 8 b * 32 st * 2 dt = 512
    int b = bx >> 6;
    int st = (bx >> 1) & 31;
    int dt = bx & 1;
    int s0 = st * 64, d0 = dt * 64;

    int sl = t >> 2, dc = t & 3;
    const u16* src = Vb + (size_t)(b * S_LEN + s0 + sl) * HDIM + d0 + dc * 16;
#pragma unroll
    for (int half = 0; half < 2; half++) {
        bf16x8 p = *(const bf16x8*)(src + half * 8);
        int slot = dc * 2 + half;
        *(bf16x8*)((char*)tl + sl * 128 + ((slot ^ (sl & 7)) << 4)) = p;
    }
    __syncthreads();
    int dl = t >> 2, sc = t & 3;
    u16* dst = Vt + (size_t)(b * HDIM + d0 + dl) * S_LEN + s0 + sc * 16;
#pragma unroll
    for (int half = 0; half < 2; half++) {
        bf16x8 p;
#pragma unroll
        for (int j = 0; j < 8; j++) {
            int s = sc * 16 + half * 8 + j;
            p[j] = *(u16*)((char*)tl + s * 128 + (((dl >> 3) ^ (s & 7)) << 4) + (dl & 7) * 2);
        }
        *(bf16x8*)(dst + half * 8) = p;
    }
}

// ---------------- causal flash attention: 4 waves per block split the KV range of ONE
// 16-row Q tile (kt = wv, wv+4, ...); no barriers in main loop; LDS merge at the end.
// 4096 waves total = 4 waves/SIMD. K/V read directly from L2 (KV L2-resident per XCD).
__launch_bounds__(256, 4)
__global__ void attn(const u16* __restrict__ Qb, const u16* __restrict__ Kb,
                     const u16* __restrict__ Vt, float* __restrict__ out) {
    __shared__ char lds[33280];          // Om[4][16][128] f32 (32768) + ml[4][16][2] f32 (512)
    float* Om = (float*)lds;
    float* ml = (float*)(lds + 32768);

    int t = threadIdx.x;
    int wv = t >> 6, l = t & 63, lr = l & 15, lq = l >> 4;
    int bx = blockIdx.x;                 // 1024 = 8 b x 128 qt
    int b = bx & 7;                      // batch == XCD for KV L2 locality
    int qt = 127 - (bx >> 3);            // descending work order
    int qr0 = qt * 16;
    size_t qbase = (size_t)b * S_LEN;
    // P tile aliases this wave's own Om region (first 2 KB); safe: the wave overwrites
    // it with Om data only after its last P read, and no other wave touches it.
    char* Pw = lds + wv * 8192;

    bf16x8 aqf[4];
#pragma unroll
    for (int kk = 0; kk < 4; kk++)
        aqf[kk] = *(const bf16x8*)(Qb + (qbase + qr0 + lr) * HDIM + kk * 32 + lq * 8);

    f32x4 o_acc[8] = {};
    float m_run[4], l_run[4];
#pragma unroll
    for (int r = 0; r < 4; r++) { m_run[r] = -1e38f; l_run[r] = 0.f; }

    int ktd = qt >> 2;                   // diagonal 64-wide tile index
    const u16* Kbase = Kb + qbase * HDIM;
    const u16* Vbase = Vt + (size_t)b * HDIM * S_LEN;

    for (int kt = wv; kt <= ktd; kt += 4) {
        int kv0 = kt * 64;

        // S = Q K^T : K fragments straight from global (L2-hit)
        f32x4 sa[4] = {};
#pragma unroll
        for (int kk = 0; kk < 4; kk++) {
            bf16x8 bk8[4];
#pragma unroll
            for (int n = 0; n < 4; n++)
                bk8[n] = *(const bf16x8*)(Kbase + (size_t)(kv0 + n * 16 + lr) * HDIM + kk * 32 + lq * 8);
            __builtin_amdgcn_s_setprio(1);
#pragma unroll
            for (int n = 0; n < 4; n++)
                sa[n] = __builtin_amdgcn_mfma_f32_16x16x32_bf16(aqf[kk], bk8[n], sa[n], 0, 0, 0);
            __builtin_amdgcn_s_setprio(0);
        }

        if (kt == ktd) {                 // causal mask on the diagonal tile
#pragma unroll
            for (int n = 0; n < 4; n++) {
                int col = kv0 + n * 16 + lr;
#pragma unroll
                for (int r = 0; r < 4; r++) {
                    int row = qr0 + lq * 4 + r;
                    if (col > row) sa[n][r] = -1e30f;
                }
            }
        }

        // online softmax (16-lane groups own 4 q-rows each)
        float pexp[4][4];
#pragma unroll
        for (int r = 0; r < 4; r++) {
            float mx = fmaxf(fmaxf(sa[0][r], sa[1][r]), fmaxf(sa[2][r], sa[3][r]));
#pragma unroll
            for (int off = 8; off >= 1; off >>= 1) mx = fmaxf(mx, __shfl_xor(mx, off, 64));
            float mnew = fmaxf(m_run[r], mx);
            float f = __expf(m_run[r] - mnew);
            float rs = 0.f;
#pragma unroll
            for (int n = 0; n < 4; n++) { float e = __expf(sa[n][r] - mnew); pexp[n][r] = e; rs += e; }
#pragma unroll
            for (int off = 8; off >= 1; off >>= 1) rs += __shfl_xor(rs, off, 64);
            l_run[r] = l_run[r] * f + rs;
            m_run[r] = mnew;
#pragma unroll
            for (int n = 0; n < 8; n++) o_acc[n][r] *= f;
        }

        // P -> wave-private LDS (single-wave ordering; no barrier)
#pragma unroll
        for (int n = 0; n < 4; n++) {
            int col = n * 16 + lr;
            int slot = col >> 3;
            int within = (col & 7) * 2;
#pragma unroll
            for (int r = 0; r < 4; r++) {
                int row = lq * 4 + r;
                *(u16*)(Pw + row * 128 + ((slot ^ (row & 7)) << 4) + within) = f2bf(pexp[n][r]);
            }
        }

        // O += P V : V fragments straight from global (L2-hit)
#pragma unroll
        for (int kk = 0; kk < 2; kk++) {
            int slot = kk * 4 + lq;
            bf16x8 pa = *(bf16x8*)(Pw + lr * 128 + ((slot ^ (lr & 7)) << 4));
#pragma unroll
            for (int n = 0; n < 8; n++) {
                bf16x8 vb8 = *(const bf16x8*)(Vbase + (size_t)(n * 16 + lr) * S_LEN + kv0 + kk * 32 + lq * 8);
                o_acc[n] = __builtin_amdgcn_mfma_f32_16x16x32_bf16(pa, vb8, o_acc[n], 0, 0, 0);
            }
        }
    }

    // write partials (Om[wv] overwrites this wave's P area only after its last P read)
    __builtin_amdgcn_sched_barrier(0);
#pragma unroll
    for (int n = 0; n < 8; n++)
#pragma unroll
        for (int r = 0; r < 4; r++)
            Om[wv * 2048 + (lq * 4 + r) * 128 + n * 16 + lr] = o_acc[n][r];
    if (lr == 0) {
#pragma unroll
        for (int r = 0; r < 4; r++) {
            ml[wv * 32 + (lq * 4 + r) * 2 + 0] = m_run[r];
            ml[wv * 32 + (lq * 4 + r) * 2 + 1] = l_run[r];
        }
    }
    __syncthreads();

    // merge the 4 partials: 256 threads, thread -> (row = t>>4, cols (t&15)*8 .. +8)
    {
        int row = t >> 4, c0 = (t & 15) * 8;
        float m4[4], l4[4];
#pragma unroll
        for (int w = 0; w < 4; w++) {
            m4[w] = ml[w * 32 + row * 2 + 0];
            l4[w] = ml[w * 32 + row * 2 + 1];
        }
        float ms = fmaxf(fmaxf(m4[0], m4[1]), fmaxf(m4[2], m4[3]));
        float wt[4], ls = 0.f;
#pragma unroll
        for (int w = 0; w < 4; w++) { wt[w] = __expf(m4[w] - ms); ls += l4[w] * wt[w]; }
        float inv = 1.0f / ls;
        f32x4 r0 = (f32x4)0.f, r1 = (f32x4)0.f;
#pragma unroll
        for (int w = 0; w < 4; w++) {
            const f32x4* Op = (const f32x4*)(Om + w * 2048 + row * 128 + c0);
            r0 += Op[0] * wt[w];
            r1 += Op[1] * wt[w];
        }
        f32x4* dst = (f32x4*)(out + (qbase + qr0 + row) * HDIM + c0);
        dst[0] = r0 * inv;
        dst[1] = r1 * inv;
    }
}

extern "C" void kernel_launch(void* const* d_in, const int* in_sizes, int n_in,
                              void* d_out, int out_size, void* d_ws, size_t ws_size,
                              hipStream_t stream) {
    const float* hs = (const float*)d_in[0];
    const float* Wq = (const float*)d_in[1];
    const float* bq = (const float*)d_in[2];
    const float* Wk = (const float*)d_in[3];
    const float* bk = (const float*)d_in[4];
    const float* Wv = (const float*)d_in[5];
    const float* bv = (const float*)d_in[6];
    float* out = (float*)d_out;

    char* ws = (char*)d_ws;
    u16* Qb = (u16*)(ws);                       // 4 MB  [16384][128] bf16 (pre-scaled)
    u16* Kb = (u16*)(ws + (size_t)(4  << 20));  // 4 MB
    u16* Vb = (u16*)(ws + (size_t)(8  << 20));  // 4 MB
    u16* Vt = (u16*)(ws + (size_t)(12 << 20));  // 4 MB  [8][128][2048]
    u16* Wp = (u16*)(ws + (size_t)(16 << 20));  // 1.5 MB [384][2048]

    hipLaunchKernelGGL(pack_weights, dim3(192), dim3(256), 0, stream, Wq, Wk, Wv, Wp);
    hipLaunchKernelGGL(qkv_gemm, dim3(512), dim3(512), 0, stream, hs, Wp, bq, bk, bv, Qb, Kb, Vb);
    hipLaunchKernelGGL(transpose_v, dim3(512), dim3(256), 0, stream, Vb, Vt);
    hipLaunchKernelGGL(attn, dim3(1024), dim3(256), 0, stream, Qb, Kb, Vt, out);
}

// Round 5
// 149.135 us; speedup vs baseline: 1.5097x; 1.1589x over previous
//
#include <hip/hip_runtime.h>
#include <hip/hip_bf16.h>
#include <stdint.h>

#define B_DIM 8
#define S_LEN 2048
#define DMODEL 2048
#define HDIM 128

typedef __attribute__((ext_vector_type(4))) float f32x4;
typedef __attribute__((ext_vector_type(8))) short bf16x8;
typedef __attribute__((ext_vector_type(4))) short bf16x4;
typedef __attribute__((ext_vector_type(4))) unsigned int u32x4;
typedef unsigned short u16;
typedef unsigned int u32;

__device__ __forceinline__ u16 f2bf(float f) {
    union { float f; u32 u; } v; v.f = f;
    u32 u = v.u;
    u32 r = (u + 0x7fffu + ((u >> 16) & 1u)) >> 16;
    return (u16)r;
}

__device__ __forceinline__ u32 pk2bf(float a, float b) {
    float2 f2; f2.x = a; f2.y = b;
    __hip_bfloat162 h = __float22bfloat162_rn(f2);
    union { __hip_bfloat162 h; u32 u; } cv; cv.h = h;
    return cv.u;
}

__device__ __forceinline__ void async_copy16(u16* lds, const u16* g) {
    __builtin_amdgcn_global_load_lds((const __attribute__((address_space(1))) u32*)g,
                                     (__attribute__((address_space(3))) u32*)lds,
                                     16, 0, 0);
}

// ---------------- pack weights: transpose [2048 k][128 h] fp32 x3 -> bf16 Wp[384 h][2048 k]
__global__ void pack_weights(const float* __restrict__ Wq, const float* __restrict__ Wk,
                             const float* __restrict__ Wv, u16* __restrict__ Wp) {
    __shared__ u16 tl[64 * 64];
    int t = threadIdx.x;
    int bx = blockIdx.x;                 // 3 w * 32 kt * 2 ht = 192
    int w = bx >> 6;
    int kt = (bx >> 1) & 31;
    int ht = bx & 1;
    int k0 = kt * 64, h0 = ht * 64;
    const float* W = (w == 0) ? Wq : ((w == 1) ? Wk : Wv);

    int kl = t >> 2, hc = t & 3;
    const float* src = W + (size_t)(k0 + kl) * HDIM + h0 + hc * 16;
#pragma unroll
    for (int half = 0; half < 2; half++) {
        bf16x8 p;
#pragma unroll
        for (int j = 0; j < 8; j++) p[j] = (short)f2bf(src[half * 8 + j]);
        int slot = hc * 2 + half;
        *(bf16x8*)((char*)tl + kl * 128 + ((slot ^ (kl & 7)) << 4)) = p;
    }
    __syncthreads();
    int hl = t >> 2, kc = t & 3;
    u16* dst = Wp + (size_t)(w * HDIM + h0 + hl) * DMODEL + k0 + kc * 16;
#pragma unroll
    for (int half = 0; half < 2; half++) {
        bf16x8 p;
#pragma unroll
        for (int j = 0; j < 8; j++) {
            int k = kc * 16 + half * 8 + j;
            p[j] = *(u16*)((char*)tl + k * 128 + (((hl >> 3) ^ (k & 7)) << 4) + (hl & 7) * 2);
        }
        *(bf16x8*)(dst + half * 8) = p;
    }
}

// ---------------- fused QKV projection GEMM: [16384,2048] @ [2048,384] (bf16 MFMA)
// BM=64, BN=384 (A read once), BK=64, grid 256, 8 waves (2m x 4n, wave tile 32x96).
// Counted-vmcnt pipeline: raw s_barrier; B-DMA of tile i+1 waited with vmcnt(2)
// (flew during compute); A-loads of tile i+2 stay IN FLIGHT across the barrier.
// V columns written directly transposed -> Vt[b][h][s].
__launch_bounds__(512)
__global__ void qkv_gemm(const float* __restrict__ hs, const u16* __restrict__ Wp,
                         const float* __restrict__ bq, const float* __restrict__ bk,
                         const float* __restrict__ bv,
                         u16* __restrict__ Qb, u16* __restrict__ Kb, u16* __restrict__ Vt) {
    __shared__ u16 As[2][64 * 64];       // 2 x 8 KB, 16B-slot XOR swizzle
    __shared__ u16 Bs[2][384 * 64];      // 2 x 48 KB, swizzled

    int t = threadIdx.x;
    int wv = t >> 6, l = t & 63, lr = l & 15, lq = l >> 4;
    int wm = wv >> 2, wn = wv & 3;
    int m0 = blockIdx.x * 64;

    f32x4 acc[2][6] = {};

    int ar = t >> 3, aq = t & 7;         // A staging: row 0..63, 8-float chunk 0..7
    const float* gA = hs + (size_t)(m0 + ar) * DMODEL + aq * 8;

    f32x4 p0A, p1A, p0B, p1B;            // two A-prefetch register sets (depth 2)

#define STAGE_B(K0, BUF)                                                    \
    {                                                                       \
        _Pragma("unroll")                                                   \
        for (int i = 0; i < 6; i++) {                                       \
            int c = i * 512 + t;                                            \
            int n = c >> 3, s = c & 7;                                      \
            async_copy16(&Bs[BUF][c * 8],                                   \
                         Wp + (size_t)n * DMODEL + (K0) + ((s ^ (n & 7)) * 8)); \
        }                                                                   \
    }
#define WRITE_A(BUF, V0, V1)                                                \
    {                                                                       \
        u32x4 pk;                                                           \
        pk.x = pk2bf(V0[0], V0[1]); pk.y = pk2bf(V0[2], V0[3]);             \
        pk.z = pk2bf(V1[0], V1[1]); pk.w = pk2bf(V1[2], V1[3]);             \
        *(u32x4*)((char*)&As[BUF][0] + ar * 128 + ((aq ^ (ar & 7)) << 4)) = pk; \
    }
#define COMPUTE(CUR)                                                        \
    {                                                                       \
        _Pragma("unroll")                                                   \
        for (int kk = 0; kk < 2; kk++) {                                    \
            bf16x8 afr[2], bfr[6];                                          \
            int slot = kk * 4 + lq;                                         \
            _Pragma("unroll")                                               \
            for (int mi = 0; mi < 2; mi++) {                                \
                int row = wm * 32 + mi * 16 + lr;                           \
                afr[mi] = *(bf16x8*)((char*)&As[CUR][0] + row * 128 + ((slot ^ (row & 7)) << 4)); \
            }                                                               \
            _Pragma("unroll")                                               \
            for (int ni = 0; ni < 6; ni++) {                                \
                int row = wn * 96 + ni * 16 + lr;                           \
                bfr[ni] = *(bf16x8*)((char*)&Bs[CUR][0] + row * 128 + ((slot ^ (row & 7)) << 4)); \
            }                                                               \
            __builtin_amdgcn_s_setprio(1);                                  \
            _Pragma("unroll")                                               \
            for (int mi = 0; mi < 2; mi++)                                  \
                _Pragma("unroll")                                           \
                for (int ni = 0; ni < 6; ni++)                              \
                    acc[mi][ni] = __builtin_amdgcn_mfma_f32_16x16x32_bf16(afr[mi], bfr[ni], acc[mi][ni], 0, 0, 0); \
            __builtin_amdgcn_s_setprio(0);                                  \
        }                                                                   \
    }
#define SYNC_PIPE                                                           \
    asm volatile("s_waitcnt vmcnt(2) lgkmcnt(0)" ::: "memory");             \
    __builtin_amdgcn_sched_barrier(0);                                      \
    __builtin_amdgcn_s_barrier();                                           \
    __builtin_amdgcn_sched_barrier(0);

    // prologue: tile 0 into buf0; prefetch A(1)
    p0A = *(const f32x4*)(gA + 0); p1A = *(const f32x4*)(gA + 4);
    STAGE_B(0, 0);
    WRITE_A(0, p0A, p1A);
    p0A = *(const f32x4*)(gA + 64); p1A = *(const f32x4*)(gA + 68);
    __syncthreads();                     // full drain once (prologue only)

    for (int k0 = 0; k0 < DMODEL; k0 += 128) {
        // even step: compute buf0; stage tile(i+1)->buf1; prefetch A(i+2)
        {
            int ks = (k0 + 64) & (DMODEL - 1);
            int kp = (k0 + 128) & (DMODEL - 1);
            STAGE_B(ks, 1);
            p0B = *(const f32x4*)(gA + kp); p1B = *(const f32x4*)(gA + kp + 4);
            COMPUTE(0);
            WRITE_A(1, p0A, p1A);
            SYNC_PIPE
        }
        // odd step: compute buf1; stage->buf0; prefetch
        {
            int ks = (k0 + 128) & (DMODEL - 1);
            int kp = (k0 + 192) & (DMODEL - 1);
            STAGE_B(ks, 0);
            p0A = *(const f32x4*)(gA + kp); p1A = *(const f32x4*)(gA + kp + 4);
            COMPUTE(1);
            WRITE_A(0, p0B, p1B);
            SYNC_PIPE
        }
    }

    // epilogue: bias; Q pre-scaled by 1/sqrt(128); V written transposed to Vt[b][h][s]
#pragma unroll
    for (int ni = 0; ni < 6; ni++) {
        int col = wn * 96 + ni * 16 + lr;
        int w = col >> 7, h = col & 127;
        const float* bp = (w == 0) ? bq : ((w == 1) ? bk : bv);
        float bias = bp[h];
#pragma unroll
        for (int mi = 0; mi < 2; mi++) {
            int row0 = m0 + wm * 32 + mi * 16 + lq * 4;
            if (w == 2) {
                int b = row0 >> 11, s0 = row0 & (S_LEN - 1);
                bf16x4 pv;
#pragma unroll
                for (int r = 0; r < 4; r++) pv[r] = (short)f2bf(acc[mi][ni][r] + bias);
                *(bf16x4*)(Vt + (size_t)(b * HDIM + h) * S_LEN + s0) = pv;
            } else {
                float scale = (w == 0) ? 0.08838834764831845f : 1.0f;
                u16* dst = (w == 0) ? Qb : Kb;
#pragma unroll
                for (int r = 0; r < 4; r++)
                    dst[(size_t)(row0 + r) * HDIM + h] = f2bf((acc[mi][ni][r] + bias) * scale);
            }
        }
    }
#undef STAGE_B
#undef WRITE_A
#undef COMPUTE
#undef SYNC_PIPE
}

// ---------------- causal flash attention: 4 waves per block split the KV range of ONE
// 16-row Q tile (kt = wv, wv+4, ...); no barriers in main loop; LDS merge at the end.
// 4096 waves = 4 waves/SIMD. K/V read directly from L2 (KV L2-resident per XCD).
__launch_bounds__(256, 4)
__global__ void attn(const u16* __restrict__ Qb, const u16* __restrict__ Kb,
                     const u16* __restrict__ Vt, float* __restrict__ out) {
    __shared__ char lds[33280];          // Om[4][16][128] f32 (32768) + ml[4][16][2] f32 (512)
    float* Om = (float*)lds;
    float* ml = (float*)(lds + 32768);

    int t = threadIdx.x;
    int wv = t >> 6, l = t & 63, lr = l & 15, lq = l >> 4;
    int bx = blockIdx.x;                 // 1024 = 8 b x 128 qt
    int b = bx & 7;                      // batch == XCD for KV L2 locality
    int qt = 127 - (bx >> 3);            // descending work order
    int qr0 = qt * 16;
    size_t qbase = (size_t)b * S_LEN;
    char* Pw = lds + wv * 8192;          // P tile aliases this wave's own Om region

    bf16x8 aqf[4];
#pragma unroll
    for (int kk = 0; kk < 4; kk++)
        aqf[kk] = *(const bf16x8*)(Qb + (qbase + qr0 + lr) * HDIM + kk * 32 + lq * 8);

    f32x4 o_acc[8] = {};
    float m_run[4], l_run[4];
#pragma unroll
    for (int r = 0; r < 4; r++) { m_run[r] = -1e38f; l_run[r] = 0.f; }

    int ktd = qt >> 2;                   // diagonal 64-wide tile index
    const u16* Kbase = Kb + qbase * HDIM;
    const u16* Vbase = Vt + (size_t)b * HDIM * S_LEN;

    for (int kt = wv; kt <= ktd; kt += 4) {
        int kv0 = kt * 64;

        // S = Q K^T : K fragments straight from global (L2-hit), batched loads
        f32x4 sa[4] = {};
#pragma unroll
        for (int kk = 0; kk < 4; kk++) {
            bf16x8 bk8[4];
#pragma unroll
            for (int n = 0; n < 4; n++)
                bk8[n] = *(const bf16x8*)(Kbase + (size_t)(kv0 + n * 16 + lr) * HDIM + kk * 32 + lq * 8);
            __builtin_amdgcn_s_setprio(1);
#pragma unroll
            for (int n = 0; n < 4; n++)
                sa[n] = __builtin_amdgcn_mfma_f32_16x16x32_bf16(aqf[kk], bk8[n], sa[n], 0, 0, 0);
            __builtin_amdgcn_s_setprio(0);
        }

        if (kt == ktd) {                 // causal mask on the diagonal tile
#pragma unroll
            for (int n = 0; n < 4; n++) {
                int col = kv0 + n * 16 + lr;
#pragma unroll
                for (int r = 0; r < 4; r++) {
                    int row = qr0 + lq * 4 + r;
                    if (col > row) sa[n][r] = -1e30f;
                }
            }
        }

        // online softmax (16-lane groups own 4 q-rows each; 4 independent chains)
        float pexp[4][4];
#pragma unroll
        for (int r = 0; r < 4; r++) {
            float mx = fmaxf(fmaxf(sa[0][r], sa[1][r]), fmaxf(sa[2][r], sa[3][r]));
#pragma unroll
            for (int off = 8; off >= 1; off >>= 1) mx = fmaxf(mx, __shfl_xor(mx, off, 64));
            float mnew = fmaxf(m_run[r], mx);
            float f = __expf(m_run[r] - mnew);
            float rs = 0.f;
#pragma unroll
            for (int n = 0; n < 4; n++) { float e = __expf(sa[n][r] - mnew); pexp[n][r] = e; rs += e; }
#pragma unroll
            for (int off = 8; off >= 1; off >>= 1) rs += __shfl_xor(rs, off, 64);
            l_run[r] = l_run[r] * f + rs;
            m_run[r] = mnew;
#pragma unroll
            for (int n = 0; n < 8; n++) o_acc[n][r] *= f;
        }

        // P -> wave-private LDS (single-wave ordering; no barrier)
#pragma unroll
        for (int n = 0; n < 4; n++) {
            int col = n * 16 + lr;
            int slot = col >> 3;
            int within = (col & 7) * 2;
#pragma unroll
            for (int r = 0; r < 4; r++) {
                int row = lq * 4 + r;
                *(u16*)(Pw + row * 128 + ((slot ^ (row & 7)) << 4) + within) = f2bf(pexp[n][r]);
            }
        }

        // O += P V : batch all 8 V fragments, then MFMA cluster
#pragma unroll
        for (int kk = 0; kk < 2; kk++) {
            int slot = kk * 4 + lq;
            bf16x8 pa = *(bf16x8*)(Pw + lr * 128 + ((slot ^ (lr & 7)) << 4));
            bf16x8 vb8[8];
#pragma unroll
            for (int n = 0; n < 8; n++)
                vb8[n] = *(const bf16x8*)(Vbase + (size_t)(n * 16 + lr) * S_LEN + kv0 + kk * 32 + lq * 8);
            __builtin_amdgcn_s_setprio(1);
#pragma unroll
            for (int n = 0; n < 8; n++)
                o_acc[n] = __builtin_amdgcn_mfma_f32_16x16x32_bf16(pa, vb8[n], o_acc[n], 0, 0, 0);
            __builtin_amdgcn_s_setprio(0);
        }
    }

    // write partials (Om[wv] overwrites this wave's P area only after its last P read)
    __builtin_amdgcn_sched_barrier(0);
#pragma unroll
    for (int n = 0; n < 8; n++)
#pragma unroll
        for (int r = 0; r < 4; r++)
            Om[wv * 2048 + (lq * 4 + r) * 128 + n * 16 + lr] = o_acc[n][r];
    if (lr == 0) {
#pragma unroll
        for (int r = 0; r < 4; r++) {
            ml[wv * 32 + (lq * 4 + r) * 2 + 0] = m_run[r];
            ml[wv * 32 + (lq * 4 + r) * 2 + 1] = l_run[r];
        }
    }
    __syncthreads();

    // merge the 4 partials: thread -> (row = t>>4, cols (t&15)*8 .. +8)
    {
        int row = t >> 4, c0 = (t & 15) * 8;
        float m4[4], l4[4];
#pragma unroll
        for (int w = 0; w < 4; w++) {
            m4[w] = ml[w * 32 + row * 2 + 0];
            l4[w] = ml[w * 32 + row * 2 + 1];
        }
        float ms = fmaxf(fmaxf(m4[0], m4[1]), fmaxf(m4[2], m4[3]));
        float wt[4], ls = 0.f;
#pragma unroll
        for (int w = 0; w < 4; w++) { wt[w] = __expf(m4[w] - ms); ls += l4[w] * wt[w]; }
        float inv = 1.0f / ls;
        f32x4 r0 = (f32x4)0.f, r1 = (f32x4)0.f;
#pragma unroll
        for (int w = 0; w < 4; w++) {
            const f32x4* Op = (const f32x4*)(Om + w * 2048 + row * 128 + c0);
            r0 += Op[0] * wt[w];
            r1 += Op[1] * wt[w];
        }
        f32x4* dst = (f32x4*)(out + (qbase + qr0 + row) * HDIM + c0);
        dst[0] = r0 * inv;
        dst[1] = r1 * inv;
    }
}

extern "C" void kernel_launch(void* const* d_in, const int* in_sizes, int n_in,
                              void* d_out, int out_size, void* d_ws, size_t ws_size,
                              hipStream_t stream) {
    const float* hs = (const float*)d_in[0];
    const float* Wq = (const float*)d_in[1];
    const float* bq = (const float*)d_in[2];
    const float* Wk = (const float*)d_in[3];
    const float* bk = (const float*)d_in[4];
    const float* Wv = (const float*)d_in[5];
    const float* bv = (const float*)d_in[6];
    float* out = (float*)d_out;

    char* ws = (char*)d_ws;
    u16* Qb = (u16*)(ws);                       // 4 MB  [16384][128] bf16 (pre-scaled)
    u16* Kb = (u16*)(ws + (size_t)(4  << 20));  // 4 MB
    u16* Vt = (u16*)(ws + (size_t)(8  << 20));  // 4 MB  [8][128][2048] (written by qkv epilogue)
    u16* Wp = (u16*)(ws + (size_t)(12 << 20));  // 1.5 MB [384][2048]

    hipLaunchKernelGGL(pack_weights, dim3(192), dim3(256), 0, stream, Wq, Wk, Wv, Wp);
    hipLaunchKernelGGL(qkv_gemm, dim3(256), dim3(512), 0, stream, hs, Wp, bq, bk, bv, Qb, Kb, Vt);
    hipLaunchKernelGGL(attn, dim3(1024), dim3(256), 0, stream, Qb, Kb, Vt, out);
}